// Round 1
// baseline (811.231 us; speedup 1.0000x reference)
//
#include <hip/hip_runtime.h>
#include <hip/hip_bf16.h>
#include <stdint.h>

#define N_V   16384
#define M_E   8192
#define CIN   128
#define COUT  64
#define RCAP  128   // per-vertex edge-list capacity (Poisson(41): overflow ~1e-13)
#define CCAP  192   // per-edge vertex-list capacity (Poisson(82): overflow ~1e-18)

// workspace layout (bytes), all offsets 16B-aligned
#define OFF_ROWCNT  0
#define OFF_COLCNT  (N_V * 4)                         // 65536
#define OFF_ROWLIST (OFF_COLCNT + M_E * 4)            // 98304
#define OFF_COLLIST (OFF_ROWLIST + N_V * RCAP * 2)    // + 4 MB
#define OFF_YV      (OFF_COLLIST + M_E * CCAP * 2)    // + 3 MB
#define OFF_E       (OFF_YV + N_V * COUT * 4)         // + 4 MB
// total: OFF_E + M_E*COUT*4  ~= 13.1 MB

// ---------------------------------------------------------------------------
// K1: stream H once; build row lists (vertex -> edges), col lists
// (edge -> vertices), and degree counts via atomics.
// ---------------------------------------------------------------------------
__global__ __launch_bounds__(256) void k_sparsify(
    const float4* __restrict__ H4,
    int* __restrict__ row_cnt, int* __restrict__ col_cnt,
    unsigned short* __restrict__ row_list, unsigned short* __restrict__ col_list) {
  const int total4 = (N_V * M_E) / 4;   // 33,554,432
  const int stride = gridDim.x * blockDim.x;
  for (int idx = blockIdx.x * blockDim.x + threadIdx.x; idx < total4; idx += stride) {
    float4 v = H4[idx];
    if (v.x == 0.f && v.y == 0.f && v.z == 0.f && v.w == 0.f) continue;
    int e  = idx << 2;          // element index
    int n  = e >> 13;           // row (M_E = 2^13)
    int mb = e & (M_E - 1);     // col base
    float vals[4] = {v.x, v.y, v.z, v.w};
#pragma unroll
    for (int j = 0; j < 4; ++j) {
      if (vals[j] != 0.f) {
        int m  = mb + j;
        int rp = atomicAdd(&row_cnt[n], 1);
        if (rp < RCAP) row_list[n * RCAP + rp] = (unsigned short)m;
        int cp = atomicAdd(&col_cnt[m], 1);
        if (cp < CCAP) col_list[m * CCAP + cp] = (unsigned short)n;
      }
    }
  }
}

// ---------------------------------------------------------------------------
// K2: Yv[n,c] = dv[n] * (X[n,:] . W[c,:] + b[c])
// Lane = row; each block's 4 waves cover c-blocks 0..3 (16 channels each) of
// the same 64 rows (X quads shared via L1). W/b addresses are wave-uniform.
// ---------------------------------------------------------------------------
__global__ __launch_bounds__(256) void k_project(
    const float* __restrict__ X, const float* __restrict__ W,
    const float* __restrict__ b, const int* __restrict__ row_cnt,
    float* __restrict__ Yv) {
  int wid  = threadIdx.x >> 6;
  int lane = threadIdx.x & 63;
  int cb   = __builtin_amdgcn_readfirstlane(wid);   // c-block 0..3, forced SGPR
  int n    = blockIdx.x * 64 + lane;                // gridDim.x = 256
  const float* xrow  = X + n * CIN;
  const float* wbase = W + cb * 16 * CIN;

  float acc[16];
#pragma unroll
  for (int j = 0; j < 16; ++j) acc[j] = 0.f;

  for (int k4 = 0; k4 < CIN / 4; ++k4) {
    float4 x = *(const float4*)(xrow + k4 * 4);
#pragma unroll
    for (int j = 0; j < 16; ++j) {
      float4 w = *(const float4*)(wbase + j * CIN + k4 * 4);
      acc[j] += x.x * w.x + x.y * w.y + x.z * w.z + x.w * w.w;
    }
  }

  int cnt  = row_cnt[n];
  float dv = cnt > 0 ? rsqrtf((float)cnt) : 0.f;
  float* yrow = Yv + n * COUT + cb * 16;
#pragma unroll
  for (int g = 0; g < 4; ++g) {
    float4 o;
    o.x = dv * (acc[4 * g + 0] + b[cb * 16 + 4 * g + 0]);
    o.y = dv * (acc[4 * g + 1] + b[cb * 16 + 4 * g + 1]);
    o.z = dv * (acc[4 * g + 2] + b[cb * 16 + 4 * g + 2]);
    o.w = dv * (acc[4 * g + 3] + b[cb * 16 + 4 * g + 3]);
    *(float4*)(yrow + 4 * g) = o;
  }
}

// ---------------------------------------------------------------------------
// K3: E[m,:] = (1/de_cnt[m]) * sum_{n in col_list[m]} Yv[n,:]
// One wave per hyperedge, lane = channel. Indices 8-at-a-time (uint4) so 8
// coalesced 256B row-gathers are in flight.
// ---------------------------------------------------------------------------
__global__ __launch_bounds__(256) void k_edge(
    const float* __restrict__ Yv, const int* __restrict__ col_cnt,
    const unsigned short* __restrict__ col_list, float* __restrict__ E) {
  int wid  = threadIdx.x >> 6;
  int lane = threadIdx.x & 63;
  int m    = blockIdx.x * 4 + wid;      // gridDim.x = M_E/4
  int cnt  = col_cnt[m];
  const unsigned short* lst = col_list + m * CCAP;
  float acc = 0.f;
  int i = 0;
  for (; i + 8 <= cnt; i += 8) {
    uint4 u = *(const uint4*)(lst + i);
    int n0 = u.x & 0xffff, n1 = u.x >> 16;
    int n2 = u.y & 0xffff, n3 = u.y >> 16;
    int n4 = u.z & 0xffff, n5 = u.z >> 16;
    int n6 = u.w & 0xffff, n7 = u.w >> 16;
    float a0 = Yv[n0 * COUT + lane];
    float a1 = Yv[n1 * COUT + lane];
    float a2 = Yv[n2 * COUT + lane];
    float a3 = Yv[n3 * COUT + lane];
    float a4 = Yv[n4 * COUT + lane];
    float a5 = Yv[n5 * COUT + lane];
    float a6 = Yv[n6 * COUT + lane];
    float a7 = Yv[n7 * COUT + lane];
    acc += ((a0 + a1) + (a2 + a3)) + ((a4 + a5) + (a6 + a7));
  }
  for (; i < cnt; ++i) acc += Yv[(int)lst[i] * COUT + lane];
  float den = cnt > 0 ? 1.f / (float)cnt : 0.f;
  E[m * COUT + lane] = den * acc;
}

// ---------------------------------------------------------------------------
// K4: out[n,:] = relu(dv[n] * sum_{m in row_list[n]} E[m,:])
// ---------------------------------------------------------------------------
__global__ __launch_bounds__(256) void k_vertex(
    const float* __restrict__ E, const int* __restrict__ row_cnt,
    const unsigned short* __restrict__ row_list, float* __restrict__ out) {
  int wid  = threadIdx.x >> 6;
  int lane = threadIdx.x & 63;
  int n    = blockIdx.x * 4 + wid;      // gridDim.x = N_V/4
  int cnt  = row_cnt[n];
  const unsigned short* lst = row_list + n * RCAP;
  float acc = 0.f;
  int i = 0;
  for (; i + 8 <= cnt; i += 8) {
    uint4 u = *(const uint4*)(lst + i);
    int m0 = u.x & 0xffff, m1 = u.x >> 16;
    int m2 = u.y & 0xffff, m3 = u.y >> 16;
    int m4 = u.z & 0xffff, m5 = u.z >> 16;
    int m6 = u.w & 0xffff, m7 = u.w >> 16;
    float a0 = E[m0 * COUT + lane];
    float a1 = E[m1 * COUT + lane];
    float a2 = E[m2 * COUT + lane];
    float a3 = E[m3 * COUT + lane];
    float a4 = E[m4 * COUT + lane];
    float a5 = E[m5 * COUT + lane];
    float a6 = E[m6 * COUT + lane];
    float a7 = E[m7 * COUT + lane];
    acc += ((a0 + a1) + (a2 + a3)) + ((a4 + a5) + (a6 + a7));
  }
  for (; i < cnt; ++i) acc += E[(int)lst[i] * COUT + lane];
  float dv = cnt > 0 ? rsqrtf((float)cnt) : 0.f;
  out[n * COUT + lane] = fmaxf(dv * acc, 0.f);
}

// ---------------------------------------------------------------------------
extern "C" void kernel_launch(void* const* d_in, const int* in_sizes, int n_in,
                              void* d_out, int out_size, void* d_ws, size_t ws_size,
                              hipStream_t stream) {
  const float* X = (const float*)d_in[0];   // (N_V, CIN)
  const float* H = (const float*)d_in[1];   // (N_V, M_E)
  const float* W = (const float*)d_in[2];   // (COUT, CIN)
  const float* b = (const float*)d_in[3];   // (COUT,)
  float* out = (float*)d_out;               // (N_V, COUT) fp32

  char* ws = (char*)d_ws;
  int* row_cnt = (int*)(ws + OFF_ROWCNT);
  int* col_cnt = (int*)(ws + OFF_COLCNT);
  unsigned short* row_list = (unsigned short*)(ws + OFF_ROWLIST);
  unsigned short* col_list = (unsigned short*)(ws + OFF_COLLIST);
  float* Yv = (float*)(ws + OFF_YV);
  float* E  = (float*)(ws + OFF_E);

  // counters must be zero each call (ws is poisoned to 0xAA before every launch)
  hipMemsetAsync(ws, 0, OFF_ROWLIST, stream);

  k_sparsify<<<8192, 256, 0, stream>>>((const float4*)H, row_cnt, col_cnt,
                                       row_list, col_list);
  k_project<<<N_V / 64, 256, 0, stream>>>(X, W, b, row_cnt, Yv);
  k_edge<<<M_E / 4, 256, 0, stream>>>(Yv, col_cnt, col_list, E);
  k_vertex<<<N_V / 4, 256, 0, stream>>>(E, row_cnt, row_list, out);
}

// Round 2
// 753.445 us; speedup vs baseline: 1.0767x; 1.0767x over previous
//
#include <hip/hip_runtime.h>
#include <hip/hip_bf16.h>
#include <stdint.h>

#define N_V   16384
#define M_E   8192
#define CIN   128
#define COUT  64
#define RCAP  128   // per-vertex edge-list capacity (Poisson(41): overflow ~1e-13)
#define CCAP  192   // per-edge vertex-list capacity (Poisson(82): overflow ~1e-18)

// workspace layout (bytes), all offsets 16B-aligned
#define OFF_ROWCNT  0
#define OFF_COLCNT  (N_V * 4)                         // 65536
#define OFF_ROWLIST (OFF_COLCNT + M_E * 4)            // 98304
#define OFF_COLLIST (OFF_ROWLIST + N_V * RCAP * 2)    // + 4 MB
#define OFF_YV      (OFF_COLLIST + M_E * CCAP * 2)    // + 3 MB
#define OFF_E       (OFF_YV + N_V * COUT * 4)         // + 4 MB
// total: OFF_E + M_E*COUT*4  ~= 13.1 MB

// ---------------------------------------------------------------------------
// K1: stream H once, one wave per row. ZERO atomics: slot assignment via
// wave ballots + popcount prefix; row_cnt is a plain store at the end.
// 32 iterations x 1KB coalesced loads per wave, no dependent vmem in loop.
// ---------------------------------------------------------------------------
__global__ __launch_bounds__(256) void k_rows(
    const uint4* __restrict__ H4,
    int* __restrict__ row_cnt, unsigned short* __restrict__ row_list) {
  int wid  = threadIdx.x >> 6;
  int lane = threadIdx.x & 63;
  int n    = blockIdx.x * 4 + wid;                 // gridDim.x = N_V/4
  const uint4* rp = H4 + (size_t)n * (M_E / 4) + lane;
  unsigned short* rl = row_list + n * RCAP;
  unsigned long long lt = (lane == 63) ? 0x7fffffffffffffffull
                                       : ((1ull << lane) - 1ull);
  int off = 0;
#pragma unroll 4
  for (int it = 0; it < (M_E / 4) / 64; ++it) {    // 32 iterations
    uint4 v = rp[it * 64];
    // H entries are 0.0f / 1.0f: nonzero bits <=> nonzero float
    unsigned long long b0 = __ballot(v.x != 0u);
    unsigned long long b1 = __ballot(v.y != 0u);
    unsigned long long b2 = __ballot(v.z != 0u);
    unsigned long long b3 = __ballot(v.w != 0u);
    int t0 = __popcll(b0), t1 = __popcll(b1), t2 = __popcll(b2), t3 = __popcll(b3);
    int total = t0 + t1 + t2 + t3;
    if (total) {                                   // wave-uniform branch
      int mb = (it * 64 + lane) * 4;               // column base for this lane
      if (v.x != 0u) { int p = off + __popcll(b0 & lt);
                       if (p < RCAP) rl[p] = (unsigned short)(mb + 0); }
      if (v.y != 0u) { int p = off + t0 + __popcll(b1 & lt);
                       if (p < RCAP) rl[p] = (unsigned short)(mb + 1); }
      if (v.z != 0u) { int p = off + t0 + t1 + __popcll(b2 & lt);
                       if (p < RCAP) rl[p] = (unsigned short)(mb + 2); }
      if (v.w != 0u) { int p = off + t0 + t1 + t2 + __popcll(b3 & lt);
                       if (p < RCAP) rl[p] = (unsigned short)(mb + 3); }
      off += total;
    }
  }
  if (lane == 0) row_cnt[n] = off < RCAP ? off : RCAP;
}

// ---------------------------------------------------------------------------
// K1b: build col lists from row lists. One thread per (row, slot); 671k
// independent atomic chains fully hidden by 2M-thread parallelism.
// ---------------------------------------------------------------------------
__global__ __launch_bounds__(256) void k_cols(
    const int* __restrict__ row_cnt, const unsigned short* __restrict__ row_list,
    int* __restrict__ col_cnt, unsigned short* __restrict__ col_list) {
  int t    = blockIdx.x * 256 + threadIdx.x;       // grid = N_V*RCAP/256
  int n    = t >> 7;                               // RCAP = 128
  int slot = t & (RCAP - 1);
  if (slot < row_cnt[n]) {
    int e  = row_list[n * RCAP + slot];
    int cp = atomicAdd(&col_cnt[e], 1);
    if (cp < CCAP) col_list[e * CCAP + cp] = (unsigned short)n;
  }
}

// ---------------------------------------------------------------------------
// K2: Yv[n,c] = dv[n] * (X[n,:] . W[c,:] + b[c])
// ---------------------------------------------------------------------------
__global__ __launch_bounds__(256) void k_project(
    const float* __restrict__ X, const float* __restrict__ W,
    const float* __restrict__ b, const int* __restrict__ row_cnt,
    float* __restrict__ Yv) {
  int wid  = threadIdx.x >> 6;
  int lane = threadIdx.x & 63;
  int cb   = __builtin_amdgcn_readfirstlane(wid);   // c-block 0..3, forced SGPR
  int n    = blockIdx.x * 64 + lane;                // gridDim.x = 256
  const float* xrow  = X + n * CIN;
  const float* wbase = W + cb * 16 * CIN;

  float acc[16];
#pragma unroll
  for (int j = 0; j < 16; ++j) acc[j] = 0.f;

  for (int k4 = 0; k4 < CIN / 4; ++k4) {
    float4 x = *(const float4*)(xrow + k4 * 4);
#pragma unroll
    for (int j = 0; j < 16; ++j) {
      float4 w = *(const float4*)(wbase + j * CIN + k4 * 4);
      acc[j] += x.x * w.x + x.y * w.y + x.z * w.z + x.w * w.w;
    }
  }

  int cnt  = row_cnt[n];
  float dv = cnt > 0 ? rsqrtf((float)cnt) : 0.f;
  float* yrow = Yv + n * COUT + cb * 16;
#pragma unroll
  for (int g = 0; g < 4; ++g) {
    float4 o;
    o.x = dv * (acc[4 * g + 0] + b[cb * 16 + 4 * g + 0]);
    o.y = dv * (acc[4 * g + 1] + b[cb * 16 + 4 * g + 1]);
    o.z = dv * (acc[4 * g + 2] + b[cb * 16 + 4 * g + 2]);
    o.w = dv * (acc[4 * g + 3] + b[cb * 16 + 4 * g + 3]);
    *(float4*)(yrow + 4 * g) = o;
  }
}

// ---------------------------------------------------------------------------
// K3: E[m,:] = (1/de_cnt[m]) * sum_{n in col_list[m]} Yv[n,:]
// One wave per hyperedge, lane = channel; 8 gathers in flight.
// ---------------------------------------------------------------------------
__global__ __launch_bounds__(256) void k_edge(
    const float* __restrict__ Yv, const int* __restrict__ col_cnt,
    const unsigned short* __restrict__ col_list, float* __restrict__ E) {
  int wid  = threadIdx.x >> 6;
  int lane = threadIdx.x & 63;
  int m    = blockIdx.x * 4 + wid;      // gridDim.x = M_E/4
  int cnt  = col_cnt[m];
  if (cnt > CCAP) cnt = CCAP;
  const unsigned short* lst = col_list + m * CCAP;
  float acc = 0.f;
  int i = 0;
  for (; i + 8 <= cnt; i += 8) {
    uint4 u = *(const uint4*)(lst + i);
    int n0 = u.x & 0xffff, n1 = u.x >> 16;
    int n2 = u.y & 0xffff, n3 = u.y >> 16;
    int n4 = u.z & 0xffff, n5 = u.z >> 16;
    int n6 = u.w & 0xffff, n7 = u.w >> 16;
    float a0 = Yv[n0 * COUT + lane];
    float a1 = Yv[n1 * COUT + lane];
    float a2 = Yv[n2 * COUT + lane];
    float a3 = Yv[n3 * COUT + lane];
    float a4 = Yv[n4 * COUT + lane];
    float a5 = Yv[n5 * COUT + lane];
    float a6 = Yv[n6 * COUT + lane];
    float a7 = Yv[n7 * COUT + lane];
    acc += ((a0 + a1) + (a2 + a3)) + ((a4 + a5) + (a6 + a7));
  }
  for (; i < cnt; ++i) acc += Yv[(int)lst[i] * COUT + lane];
  int realcnt = col_cnt[m];
  float den = realcnt > 0 ? 1.f / (float)realcnt : 0.f;
  E[m * COUT + lane] = den * acc;
}

// ---------------------------------------------------------------------------
// K4: out[n,:] = relu(dv[n] * sum_{m in row_list[n]} E[m,:])
// ---------------------------------------------------------------------------
__global__ __launch_bounds__(256) void k_vertex(
    const float* __restrict__ E, const int* __restrict__ row_cnt,
    const unsigned short* __restrict__ row_list, float* __restrict__ out) {
  int wid  = threadIdx.x >> 6;
  int lane = threadIdx.x & 63;
  int n    = blockIdx.x * 4 + wid;      // gridDim.x = N_V/4
  int cnt  = row_cnt[n];
  const unsigned short* lst = row_list + n * RCAP;
  float acc = 0.f;
  int i = 0;
  for (; i + 8 <= cnt; i += 8) {
    uint4 u = *(const uint4*)(lst + i);
    int m0 = u.x & 0xffff, m1 = u.x >> 16;
    int m2 = u.y & 0xffff, m3 = u.y >> 16;
    int m4 = u.z & 0xffff, m5 = u.z >> 16;
    int m6 = u.w & 0xffff, m7 = u.w >> 16;
    float a0 = E[m0 * COUT + lane];
    float a1 = E[m1 * COUT + lane];
    float a2 = E[m2 * COUT + lane];
    float a3 = E[m3 * COUT + lane];
    float a4 = E[m4 * COUT + lane];
    float a5 = E[m5 * COUT + lane];
    float a6 = E[m6 * COUT + lane];
    float a7 = E[m7 * COUT + lane];
    acc += ((a0 + a1) + (a2 + a3)) + ((a4 + a5) + (a6 + a7));
  }
  for (; i < cnt; ++i) acc += E[(int)lst[i] * COUT + lane];
  float dv = cnt > 0 ? rsqrtf((float)cnt) : 0.f;
  out[n * COUT + lane] = fmaxf(dv * acc, 0.f);
}

// ---------------------------------------------------------------------------
extern "C" void kernel_launch(void* const* d_in, const int* in_sizes, int n_in,
                              void* d_out, int out_size, void* d_ws, size_t ws_size,
                              hipStream_t stream) {
  const float* X = (const float*)d_in[0];   // (N_V, CIN)
  const float* H = (const float*)d_in[1];   // (N_V, M_E)
  const float* W = (const float*)d_in[2];   // (COUT, CIN)
  const float* b = (const float*)d_in[3];   // (COUT,)
  float* out = (float*)d_out;               // (N_V, COUT) fp32

  char* ws = (char*)d_ws;
  int* row_cnt = (int*)(ws + OFF_ROWCNT);
  int* col_cnt = (int*)(ws + OFF_COLCNT);
  unsigned short* row_list = (unsigned short*)(ws + OFF_ROWLIST);
  unsigned short* col_list = (unsigned short*)(ws + OFF_COLLIST);
  float* Yv = (float*)(ws + OFF_YV);
  float* E  = (float*)(ws + OFF_E);

  // only col_cnt needs zeroing (row_cnt is plain-stored by k_rows)
  hipMemsetAsync(col_cnt, 0, M_E * 4, stream);

  k_rows<<<N_V / 4, 256, 0, stream>>>((const uint4*)H, row_cnt, row_list);
  k_cols<<<N_V * RCAP / 256, 256, 0, stream>>>(row_cnt, row_list, col_cnt, col_list);
  k_project<<<N_V / 64, 256, 0, stream>>>(X, W, b, row_cnt, Yv);
  k_edge<<<M_E / 4, 256, 0, stream>>>(Yv, col_cnt, col_list, E);
  k_vertex<<<N_V / 4, 256, 0, stream>>>(E, row_cnt, row_list, out);
}